// Round 16
// baseline (370.590 us; speedup 1.0000x reference)
//
#include <hip/hip_runtime.h>
#include <math.h>

#define LATENT   1024
#define WORD     64
#define NB_WORD  8192
#define BATCH    2048
#define NROWS    (BATCH * LATENT / WORD)   // 32768
#define NELEM    (BATCH * LATENT)          // 2097152

#define NCHUNK   8
#define CWCHUNK  (NB_WORD / NCHUNK)        // 1024
#define TPC      (CWCHUNK / 16)            // 64 tiles per chunk
#define NTILE    (NB_WORD / 16)            // 512 tiles
#define PKTS     (NTILE * 6 * 64)          // 196608 16B packets

typedef __attribute__((ext_vector_type(8))) __bf16 bf16x8;
typedef __attribute__((ext_vector_type(4))) float  f32x4;

// ------- kernel 1: fused e2 + epack (one emb read, r1 e2 chain order) -
__global__ __launch_bounds__(256) void vq_prep_kernel(
    const float* __restrict__ emb, float* __restrict__ e2,
    bf16x8* __restrict__ epack) {
    int m = blockIdx.x * 256 + threadIdx.x;
    int tile = m >> 4, l15 = m & 15;
    float s0 = 0.f, s1 = 0.f, s2 = 0.f, s3 = 0.f;
#pragma unroll
    for (int Ks = 0; Ks < 2; ++Ks) {
#pragma unroll
        for (int q = 0; q < 4; ++q) {
            const float4* s4 = reinterpret_cast<const float4*>(
                emb + (size_t)m * WORD + Ks * 32 + q * 8);
            float4 a = s4[0], b = s4[1];
            float tv[8] = {a.x, a.y, a.z, a.w, b.x, b.y, b.z, b.w};
            bf16x8 oh, om, ol;
#pragma unroll
            for (int e = 0; e < 8; ++e) {
                float v = tv[e];
                if ((e & 3) == 0) s0 = fmaf(v, v, s0);
                else if ((e & 3) == 1) s1 = fmaf(v, v, s1);
                else if ((e & 3) == 2) s2 = fmaf(v, v, s2);
                else s3 = fmaf(v, v, s3);
                __bf16 h  = (__bf16)v;
                float r1  = v - (float)h;
                __bf16 mm = (__bf16)r1;
                float r2  = r1 - (float)mm;
                __bf16 lo = (__bf16)r2;
                oh[e] = h; om[e] = mm; ol[e] = lo;
            }
            size_t base = ((size_t)tile * 6) * 64 + q * 16 + l15;
            epack[base + (size_t)(0 * 2 + Ks) * 64] = oh;
            epack[base + (size_t)(1 * 2 + Ks) * 64] = om;
            epack[base + (size_t)(2 * 2 + Ks) * 64] = ol;
        }
    }
    e2[m] = (s0 + s1) + (s2 + s3);
}

__device__ __forceinline__ void gload_lds16(const char* g, char* l) {
    __builtin_amdgcn_global_load_lds(
        (const __attribute__((address_space(1))) void*)g,
        (__attribute__((address_space(3))) void*)l, 16, 0, 0);
}

#define MFMA16 __builtin_amdgcn_mfma_f32_16x16x32_bf16

// ---------------- kernel 2: MFMA split-bf16 argmin --------------------
// r10 champion structure with 2 TILES PER PHASE: one 12 KB DMA batch +
// one drain+barrier per 32 codewords (was per 16). Fold(A) issues in the
// shadow of MFMA(B)'s pipe drain; only fold(B) is exposed per phase.
__global__ __launch_bounds__(256)
__attribute__((amdgpu_waves_per_eu(4, 4)))
void vq_argmin_kernel(
    const float* __restrict__ z, const bf16x8* __restrict__ epack,
    const float* __restrict__ e2, unsigned long long* __restrict__ best) {

    // phase stagger: rounds are equal-length, so initial offsets persist
    {
        int ph = blockIdx.x & 3;
        if (ph == 1) __builtin_amdgcn_s_sleep(2);
        else if (ph == 2) __builtin_amdgcn_s_sleep(4);
        else if (ph == 3) __builtin_amdgcn_s_sleep(6);
    }

    __shared__ __align__(16) char le[2 * 12288];

    const int tid   = threadIdx.x;
    const int lane  = tid & 63;
    const int wband = tid >> 6;               // 0..3
    const int l15   = lane & 15;
    const int l4    = lane >> 4;              // 0..3
    const int rowbase   = blockIdx.x * 128 + wband * 32;
    const int tile0     = blockIdx.y * TPC;
    const int chunkbase = blockIdx.y * CWCHUNK;
    const float* e2g    = e2 + chunkbase;
    const int off       = (blockIdx.x & 15) * 4;   // tile start offset (mult of 4)

    // ---- build A-frags (z 3-way bf16 split) in registers ----
    bf16x8 A[2][2][3];                         // [mt][Ks][spl]
    const float4* zf4 = reinterpret_cast<const float4*>(z);
#pragma unroll
    for (int mt = 0; mt < 2; ++mt) {
        int row = rowbase + mt * 16 + l15;
#pragma unroll
        for (int Ks = 0; Ks < 2; ++Ks) {
            float4 v0 = zf4[(size_t)row * 16 + Ks * 8 + l4 * 2];
            float4 v1 = zf4[(size_t)row * 16 + Ks * 8 + l4 * 2 + 1];
            float tv[8] = {v0.x, v0.y, v0.z, v0.w, v1.x, v1.y, v1.z, v1.w};
#pragma unroll
            for (int e = 0; e < 8; ++e) {
                float v = tv[e];
                __bf16 h  = (__bf16)v;
                float r1  = v - (float)h;
                __bf16 m  = (__bf16)r1;
                float r2  = r1 - (float)m;
                __bf16 lo = (__bf16)r2;
                A[mt][Ks][0][e] = h;
                A[mt][Ks][1][e] = m;
                A[mt][Ks][2][e] = lo;
            }
        }
    }

    // ---- prologue: DMA pair (off, off+1) into buf 0 + their e2 ----
    {
        const char* src = (const char*)epack + (size_t)(tile0 + off) * 6144;
        gload_lds16(src + wband * 1024 + lane * 16,       le + wband * 1024);
        gload_lds16(src + (4 + wband) * 1024 + lane * 16, le + (4 + wband) * 1024);
        gload_lds16(src + (8 + wband) * 1024 + lane * 16, le + (8 + wband) * 1024);
    }
    float e2nA = e2g[off * 16 + l15];
    float e2nB = e2g[(off + 1) * 16 + l15];

    float bestd[8] = {INFINITY, INFINITY, INFINITY, INFINITY,
                      INFINITY, INFINITY, INFINITY, INFINITY};
    int   bt[8]    = {0, 0, 0, 0, 0, 0, 0, 0};

// 24-MFMA cluster for one tile (champion's exact combo order)
#define CLUSTER(AC0, AC1, Bh0, Bh1, Bm0, Bm1, Bl0, Bl1)                     \
    AC0 = MFMA16(A[0][0][0], Bh0, AC0, 0, 0, 0);                            \
    AC1 = MFMA16(A[1][0][0], Bh0, AC1, 0, 0, 0);                            \
    AC0 = MFMA16(A[0][0][1], Bh0, AC0, 0, 0, 0);                            \
    AC1 = MFMA16(A[1][0][1], Bh0, AC1, 0, 0, 0);                            \
    AC0 = MFMA16(A[0][0][2], Bh0, AC0, 0, 0, 0);                            \
    AC1 = MFMA16(A[1][0][2], Bh0, AC1, 0, 0, 0);                            \
    AC0 = MFMA16(A[0][0][0], Bm0, AC0, 0, 0, 0);                            \
    AC1 = MFMA16(A[1][0][0], Bm0, AC1, 0, 0, 0);                            \
    AC0 = MFMA16(A[0][0][1], Bm0, AC0, 0, 0, 0);                            \
    AC1 = MFMA16(A[1][0][1], Bm0, AC1, 0, 0, 0);                            \
    AC0 = MFMA16(A[0][0][0], Bl0, AC0, 0, 0, 0);                            \
    AC1 = MFMA16(A[1][0][0], Bl0, AC1, 0, 0, 0);                            \
    AC0 = MFMA16(A[0][1][0], Bh1, AC0, 0, 0, 0);                            \
    AC1 = MFMA16(A[1][1][0], Bh1, AC1, 0, 0, 0);                            \
    AC0 = MFMA16(A[0][1][1], Bh1, AC0, 0, 0, 0);                            \
    AC1 = MFMA16(A[1][1][1], Bh1, AC1, 0, 0, 0);                            \
    AC0 = MFMA16(A[0][1][2], Bh1, AC0, 0, 0, 0);                            \
    AC1 = MFMA16(A[1][1][2], Bh1, AC1, 0, 0, 0);                            \
    AC0 = MFMA16(A[0][1][0], Bm1, AC0, 0, 0, 0);                            \
    AC1 = MFMA16(A[1][1][0], Bm1, AC1, 0, 0, 0);                            \
    AC0 = MFMA16(A[0][1][1], Bm1, AC0, 0, 0, 0);                            \
    AC1 = MFMA16(A[1][1][1], Bm1, AC1, 0, 0, 0);                            \
    AC0 = MFMA16(A[0][1][0], Bl1, AC0, 0, 0, 0);                            \
    AC1 = MFMA16(A[1][1][0], Bl1, AC1, 0, 0, 0);

#define FOLD(AC0, AC1, E2V, T)                                              \
    _Pragma("unroll")                                                       \
    for (int v = 0; v < 4; ++v) {                                           \
        float d0 = fmaf(-2.0f, AC0[v], E2V);                                \
        if (d0 < bestd[v])     { bestd[v]     = d0; bt[v]     = (T); }      \
        float d1 = fmaf(-2.0f, AC1[v], E2V);                                \
        if (d1 < bestd[4 + v]) { bestd[4 + v] = d1; bt[4 + v] = (T); }      \
    }

// phase: compute tile pair (TA, TB) from buf BUFOFF; stage pair (TNA,
// TNB) into the other buffer; e2 prefetched one phase ahead.
#define PHASE(BUFOFF, TA, TB, TNA, TNB)                                     \
    {                                                                       \
        asm volatile("s_waitcnt vmcnt(0)" ::: "memory");                    \
        __builtin_amdgcn_sched_barrier(0);                                  \
        __builtin_amdgcn_s_barrier();      /* buf BUFOFF fully staged */    \
        const float e2cA = e2nA, e2cB = e2nB;                               \
        const char* srcn = (const char*)epack +                             \
                           (size_t)(tile0 + (TNA)) * 6144;                  \
        char* dstn = le + ((BUFOFF) ^ 12288);                               \
        gload_lds16(srcn + wband * 1024 + lane * 16, dstn + wband * 1024);  \
        gload_lds16(srcn + (4 + wband) * 1024 + lane * 16,                  \
                    dstn + (4 + wband) * 1024);                             \
        gload_lds16(srcn + (8 + wband) * 1024 + lane * 16,                  \
                    dstn + (8 + wband) * 1024);                             \
        e2nA = e2g[(TNA) * 16 + l15];                                       \
        e2nB = e2g[(TNB) * 16 + l15];                                       \
        const char* bb = le + (BUFOFF) + lane * 16;                         \
        bf16x8 Ah0 = *reinterpret_cast<const bf16x8*>(bb);                  \
        bf16x8 Ah1 = *reinterpret_cast<const bf16x8*>(bb + 1024);           \
        bf16x8 Am0 = *reinterpret_cast<const bf16x8*>(bb + 2048);           \
        bf16x8 Am1 = *reinterpret_cast<const bf16x8*>(bb + 3072);           \
        bf16x8 Al0 = *reinterpret_cast<const bf16x8*>(bb + 4096);           \
        bf16x8 Al1 = *reinterpret_cast<const bf16x8*>(bb + 5120);           \
        bf16x8 Bh0 = *reinterpret_cast<const bf16x8*>(bb + 6144);           \
        bf16x8 Bh1 = *reinterpret_cast<const bf16x8*>(bb + 7168);           \
        bf16x8 Bm0 = *reinterpret_cast<const bf16x8*>(bb + 8192);           \
        bf16x8 Bm1 = *reinterpret_cast<const bf16x8*>(bb + 9216);           \
        bf16x8 Bl0 = *reinterpret_cast<const bf16x8*>(bb + 10240);          \
        bf16x8 Bl1 = *reinterpret_cast<const bf16x8*>(bb + 11264);          \
        f32x4 a0 = {0.f,0.f,0.f,0.f}, a1 = {0.f,0.f,0.f,0.f};               \
        f32x4 b0 = {0.f,0.f,0.f,0.f}, b1 = {0.f,0.f,0.f,0.f};               \
        __builtin_amdgcn_s_setprio(1);                                      \
        CLUSTER(a0, a1, Ah0, Ah1, Am0, Am1, Al0, Al1)                       \
        CLUSTER(b0, b1, Bh0, Bh1, Bm0, Bm1, Bl0, Bl1)                       \
        __builtin_amdgcn_s_setprio(0);                                      \
        FOLD(a0, a1, e2cA, TA)          /* hidden under MFMA(B) drain */    \
        FOLD(b0, b1, e2cB, TB)                                              \
    }

    int t0 = off;                              // multiple of 4 (mod 64)
    for (int tt = 0; tt < TPC; tt += 4) {
        const int p2 = (t0 + 2) & (TPC - 1);
        const int p4 = (t0 + 4) & (TPC - 1);   // wrap: harmless reload
        PHASE(0,     t0, t0 + 1, p2, p2 + 1);
        PHASE(12288, p2, p2 + 1, p4, p4 + 1);
        t0 = p4;
    }
#undef PHASE
#undef CLUSTER
#undef FOLD

    // ---- cross-lane min over the 16 cw-lanes, then atomicMin merge ----
    // (u64 pack: min dist, tie -> min cw == first occurrence; visit-order
    //  independent, so the tile-offset stagger is safe.)
#pragma unroll
    for (int mt = 0; mt < 2; ++mt) {
#pragma unroll
        for (int v = 0; v < 4; ++v) {
            float bd = bestd[mt * 4 + v];
            int   cw = chunkbase + bt[mt * 4 + v] * 16 + l15;
            unsigned db = __float_as_uint(bd);
            db = (db & 0x80000000u) ? ~db : (db | 0x80000000u);
            unsigned long long key =
                ((unsigned long long)db << 32) | (unsigned)cw;
#pragma unroll
            for (int off2 = 1; off2 < 16; off2 <<= 1) {
                unsigned long long o = __shfl_xor(key, off2);
                key = (o < key) ? o : key;
            }
            if (l15 == 0)
                atomicMin(&best[rowbase + mt * 16 + l4 * 4 + v], key);
        }
    }
}

// ---------------- kernel 3: gather + straight-through output + loss ---
__global__ __launch_bounds__(256) void vq_out_kernel(
    const float* __restrict__ z, const float* __restrict__ emb,
    const unsigned long long* __restrict__ best,
    float* __restrict__ out, float* __restrict__ lsum) {
    const int base = (blockIdx.x * 256 + threadIdx.x) * 8;
    const int row  = base >> 6;
    const int m    = (int)(best[row] & 0xFFFFFFFFull);

    const float4* zp = reinterpret_cast<const float4*>(z + base);
    const float4* qp = reinterpret_cast<const float4*>(emb + (size_t)m * WORD + (base & 63));
    float4* op = reinterpret_cast<float4*>(out + base);

    float s = 0.f;
#pragma unroll
    for (int i = 0; i < 2; ++i) {
        float4 zv = zp[i];
        float4 qv = qp[i];
        float dx = qv.x - zv.x, dy = qv.y - zv.y, dz = qv.z - zv.z, dw = qv.w - zv.w;
        float4 ov;
        ov.x = zv.x + dx; ov.y = zv.y + dy; ov.z = zv.z + dz; ov.w = zv.w + dw;
        op[i] = ov;
        s += dx*dx + dy*dy + dz*dz + dw*dw;
    }

#pragma unroll
    for (int off = 32; off > 0; off >>= 1) s += __shfl_down(s, off);
    __shared__ float wsum[4];
    int lane = threadIdx.x & 63, wid = threadIdx.x >> 6;
    if (lane == 0) wsum[wid] = s;
    __syncthreads();
    if (threadIdx.x == 0)
        atomicAdd(lsum, (wsum[0] + wsum[1]) + (wsum[2] + wsum[3]));
}

// ---------------- kernel 4: finalize loss -----------------------------
__global__ void vq_loss_kernel(const float* __restrict__ lsum,
                               float* __restrict__ loss_out) {
    float mean = lsum[0] * (1.0f / (float)NELEM);
    loss_out[0] = mean + 2.5f * mean;
}

extern "C" void kernel_launch(void* const* d_in, const int* in_sizes, int n_in,
                              void* d_out, int out_size, void* d_ws, size_t ws_size,
                              hipStream_t stream) {
    const float* z   = (const float*)d_in[0];   // z_mean (2048,1024)
    // d_in[1] = z_log_var, unused by the reference
    const float* emb = (const float*)d_in[2];   // (8192,64)
    float* out = (float*)d_out;                 // [z_q_st flat (2097152), loss]

    // ws layout: epack 3 MB | e2 32 KB | best 256 KB | lsum 4 B
    bf16x8* epack = (bf16x8*)d_ws;
    float*  e2    = (float*)((char*)d_ws + (size_t)PKTS * 16);
    unsigned long long* best =
        (unsigned long long*)((char*)e2 + NB_WORD * sizeof(float));
    float* lsum = (float*)((char*)best + NROWS * sizeof(unsigned long long));

    hipMemsetAsync(best, 0xFF, NROWS * sizeof(unsigned long long), stream);
    hipMemsetAsync(lsum, 0, sizeof(float), stream);

    vq_prep_kernel<<<NB_WORD / 256, 256, 0, stream>>>(emb, e2, epack);
    vq_argmin_kernel<<<dim3(NROWS / 128, NCHUNK), 256, 0, stream>>>(
        z, epack, e2, best);
    vq_out_kernel<<<NELEM / (256 * 8), 256, 0, stream>>>(z, emb, best, out, lsum);
    vq_loss_kernel<<<1, 1, 0, stream>>>(lsum, out + NELEM);
}

// Round 17
// 206.282 us; speedup vs baseline: 1.7965x; 1.7965x over previous
//
#include <hip/hip_runtime.h>
#include <math.h>

#define LATENT   1024
#define WORD     64
#define NB_WORD  8192
#define BATCH    2048
#define NROWS    (BATCH * LATENT / WORD)   // 32768
#define NELEM    (BATCH * LATENT)          // 2097152

#define NCHUNK   8
#define CWCHUNK  (NB_WORD / NCHUNK)        // 1024
#define TPC      (CWCHUNK / 16)            // 64 tiles per chunk
#define NTILE    (NB_WORD / 16)            // 512 tiles
#define PKTS     (NTILE * 6 * 64)          // 196608 16B packets

#define OUT_GRID (NELEM / (256 * 8))       // 1024 blocks

typedef __attribute__((ext_vector_type(8))) __bf16 bf16x8;
typedef __attribute__((ext_vector_type(4))) float  f32x4;

// ------- kernel 1: fused e2 + epack + buffer init (one emb read) ------
// thread m owns codeword m: e2[m] via r1's exact k&3-lane chains; packets
// p=(tile*6+spl*2+Ks)*64 + q*16 + (m&15) hold 8 bf16 of split level spl
// for k = Ks*32 + q*8 + e. Also inits best/lsum/counter (replaces the
// two hipMemsetAsync dispatches).
__global__ __launch_bounds__(256) void vq_prep_kernel(
    const float* __restrict__ emb, float* __restrict__ e2,
    bf16x8* __restrict__ epack, unsigned long long* __restrict__ best,
    float* __restrict__ lsum, unsigned* __restrict__ counter) {
    int m = blockIdx.x * 256 + threadIdx.x;
    int tile = m >> 4, l15 = m & 15;

    // init best (4 entries per thread covers NROWS=4*NB_WORD), lsum, counter
    best[m]                = ~0ull;
    best[m + NB_WORD]      = ~0ull;
    best[m + 2 * NB_WORD]  = ~0ull;
    best[m + 3 * NB_WORD]  = ~0ull;
    if (m == 0) { lsum[0] = 0.f; counter[0] = 0u; }

    float s0 = 0.f, s1 = 0.f, s2 = 0.f, s3 = 0.f;
#pragma unroll
    for (int Ks = 0; Ks < 2; ++Ks) {
#pragma unroll
        for (int q = 0; q < 4; ++q) {
            const float4* s4 = reinterpret_cast<const float4*>(
                emb + (size_t)m * WORD + Ks * 32 + q * 8);
            float4 a = s4[0], b = s4[1];
            float tv[8] = {a.x, a.y, a.z, a.w, b.x, b.y, b.z, b.w};
            bf16x8 oh, om, ol;
#pragma unroll
            for (int e = 0; e < 8; ++e) {
                float v = tv[e];
                // e2 partial chains (same order as r1: s_{k&3}, k ascending)
                if ((e & 3) == 0) s0 = fmaf(v, v, s0);
                else if ((e & 3) == 1) s1 = fmaf(v, v, s1);
                else if ((e & 3) == 2) s2 = fmaf(v, v, s2);
                else s3 = fmaf(v, v, s3);
                __bf16 h  = (__bf16)v;
                float r1  = v - (float)h;
                __bf16 mm = (__bf16)r1;
                float r2  = r1 - (float)mm;
                __bf16 lo = (__bf16)r2;
                oh[e] = h; om[e] = mm; ol[e] = lo;
            }
            size_t base = ((size_t)tile * 6) * 64 + q * 16 + l15;
            epack[base + (size_t)(0 * 2 + Ks) * 64] = oh;
            epack[base + (size_t)(1 * 2 + Ks) * 64] = om;
            epack[base + (size_t)(2 * 2 + Ks) * 64] = ol;
        }
    }
    e2[m] = (s0 + s1) + (s2 + s3);
}

__device__ __forceinline__ void gload_lds16(const char* g, char* l) {
    __builtin_amdgcn_global_load_lds(
        (const __attribute__((address_space(1))) void*)g,
        (__attribute__((address_space(3))) void*)l, 16, 0, 0);
}

// ---------------- kernel 2: MFMA split-bf16 argmin (r10 champion) -----
// 256 thr = 4 waves; block = 128 rows x 1024-cw chunk; wave = 32 rows.
// 2-phase raw-barrier schedule + delayed fold: fold(phase t-1) executes
// inside phase t's ds_read latency window; only the last fold is exposed
// (epilogue). First fold is a no-op via e2prev=+INF.
__global__ __launch_bounds__(256)
__attribute__((amdgpu_waves_per_eu(4, 8)))
void vq_argmin_kernel(
    const float* __restrict__ z, const bf16x8* __restrict__ epack,
    const float* __restrict__ e2, unsigned long long* __restrict__ best) {

    // phase stagger: rounds are equal-length, so initial offsets persist
    {
        int ph = blockIdx.x & 3;
        if (ph == 1) __builtin_amdgcn_s_sleep(2);
        else if (ph == 2) __builtin_amdgcn_s_sleep(4);
        else if (ph == 3) __builtin_amdgcn_s_sleep(6);
    }

    __shared__ __align__(16) char le[2 * 6144];

    const int tid   = threadIdx.x;
    const int lane  = tid & 63;
    const int wband = tid >> 6;               // 0..3
    const int l15   = lane & 15;
    const int l4    = lane >> 4;              // 0..3
    const int rowbase   = blockIdx.x * 128 + wband * 32;
    const int tile0     = blockIdx.y * TPC;
    const int chunkbase = blockIdx.y * CWCHUNK;
    const float* e2g    = e2 + chunkbase;
    const int off       = (blockIdx.x & 15) * 4;   // tile start offset

    // ---- build A-frags (z 3-way bf16 split) in registers ----
    bf16x8 A[2][2][3];                         // [mt][Ks][spl]
    const float4* zf4 = reinterpret_cast<const float4*>(z);
#pragma unroll
    for (int mt = 0; mt < 2; ++mt) {
        int row = rowbase + mt * 16 + l15;
#pragma unroll
        for (int Ks = 0; Ks < 2; ++Ks) {
            float4 v0 = zf4[(size_t)row * 16 + Ks * 8 + l4 * 2];
            float4 v1 = zf4[(size_t)row * 16 + Ks * 8 + l4 * 2 + 1];
            float tv[8] = {v0.x, v0.y, v0.z, v0.w, v1.x, v1.y, v1.z, v1.w};
#pragma unroll
            for (int e = 0; e < 8; ++e) {
                float v = tv[e];
                __bf16 h  = (__bf16)v;
                float r1  = v - (float)h;
                __bf16 m  = (__bf16)r1;
                float r2  = r1 - (float)m;
                __bf16 lo = (__bf16)r2;
                A[mt][Ks][0][e] = h;
                A[mt][Ks][1][e] = m;
                A[mt][Ks][2][e] = lo;
            }
        }
    }

    // ---- issue DMA for tile 'off' into buf 0; prefetch its e2 ----
    {
        const char* src = (const char*)epack + (size_t)(tile0 + off) * 6144;
        gload_lds16(src + wband * 1024 + lane * 16, le + wband * 1024);
        if (wband < 2)
            gload_lds16(src + (4 + wband) * 1024 + lane * 16,
                        le + (4 + wband) * 1024);
    }
    float e2next = e2g[off * 16 + l15];

    float bestd[8] = {INFINITY, INFINITY, INFINITY, INFINITY,
                      INFINITY, INFINITY, INFINITY, INFINITY};
    int   bt[8]    = {0, 0, 0, 0, 0, 0, 0, 0};

    // delayed-fold state: previous phase's accs (first fold is a no-op:
    // fmaf(-2, 0, +INF) = +INF, never < bestd)
    f32x4 pacc0 = {0.f, 0.f, 0.f, 0.f};
    f32x4 pacc1 = {0.f, 0.f, 0.f, 0.f};
    float e2prev = INFINITY;
    int   tprev  = 0;

    for (int tt = 0; tt < TPC; ++tt) {
        const int buf = tt & 1;
        const int t   = (tt + off) & (TPC - 1);       // actual tile index

        // drain own DMA(t) + e2(t) (issued a full phase ago), raw barrier
        asm volatile("s_waitcnt vmcnt(0)" ::: "memory");
        __builtin_amdgcn_sched_barrier(0);
        __builtin_amdgcn_s_barrier();          // all waves' DMA(t) complete

        const float e2v = e2next;              // landed last phase

        // ---- issue DMA(t+1) into buf^1 + e2 prefetch (cross barrier) ----
        {
            const int tn = (tt + 1 + off) & (TPC - 1);  // wrap: harmless reload
            const char* src = (const char*)epack + (size_t)(tile0 + tn) * 6144;
            char* dst = le + (buf ^ 1) * 6144;
            gload_lds16(src + wband * 1024 + lane * 16, dst + wband * 1024);
            if (wband < 2)
                gload_lds16(src + (4 + wband) * 1024 + lane * 16,
                            dst + (4 + wband) * 1024);
            e2next = e2g[tn * 16 + l15];
        }

        // ---- issue all 6 B-frag reads (latency hidden by fold below) ----
        const char* b0 = le + buf * 6144 + lane * 16;
        bf16x8 Bh0 = *reinterpret_cast<const bf16x8*>(b0);
        bf16x8 Bm0 = *reinterpret_cast<const bf16x8*>(b0 + 2048);
        bf16x8 Bl0 = *reinterpret_cast<const bf16x8*>(b0 + 4096);
        bf16x8 Bh1 = *reinterpret_cast<const bf16x8*>(b0 + 1024);
        bf16x8 Bm1 = *reinterpret_cast<const bf16x8*>(b0 + 3072);
        bf16x8 Bl1 = *reinterpret_cast<const bf16x8*>(b0 + 5120);

        // ---- fold PREVIOUS phase (independent of the reads above) ----
#pragma unroll
        for (int v = 0; v < 4; ++v) {
            float d0 = fmaf(-2.0f, pacc0[v], e2prev);
            if (d0 < bestd[v])     { bestd[v]     = d0; bt[v]     = tprev; }
            float d1 = fmaf(-2.0f, pacc1[v], e2prev);
            if (d1 < bestd[4 + v]) { bestd[4 + v] = d1; bt[4 + v] = tprev; }
        }

        // ---- compute on buf ----
        f32x4 acc0 = {0.f, 0.f, 0.f, 0.f};
        f32x4 acc1 = {0.f, 0.f, 0.f, 0.f};
        __builtin_amdgcn_s_setprio(1);
        // combos: hh, mh, lh, hm, mm, hl  (x 2 row-tiles), Ks=0 then Ks=1
        acc0 = __builtin_amdgcn_mfma_f32_16x16x32_bf16(A[0][0][0], Bh0, acc0, 0, 0, 0);
        acc1 = __builtin_amdgcn_mfma_f32_16x16x32_bf16(A[1][0][0], Bh0, acc1, 0, 0, 0);
        acc0 = __builtin_amdgcn_mfma_f32_16x16x32_bf16(A[0][0][1], Bh0, acc0, 0, 0, 0);
        acc1 = __builtin_amdgcn_mfma_f32_16x16x32_bf16(A[1][0][1], Bh0, acc1, 0, 0, 0);
        acc0 = __builtin_amdgcn_mfma_f32_16x16x32_bf16(A[0][0][2], Bh0, acc0, 0, 0, 0);
        acc1 = __builtin_amdgcn_mfma_f32_16x16x32_bf16(A[1][0][2], Bh0, acc1, 0, 0, 0);
        acc0 = __builtin_amdgcn_mfma_f32_16x16x32_bf16(A[0][0][0], Bm0, acc0, 0, 0, 0);
        acc1 = __builtin_amdgcn_mfma_f32_16x16x32_bf16(A[1][0][0], Bm0, acc1, 0, 0, 0);
        acc0 = __builtin_amdgcn_mfma_f32_16x16x32_bf16(A[0][0][1], Bm0, acc0, 0, 0, 0);
        acc1 = __builtin_amdgcn_mfma_f32_16x16x32_bf16(A[1][0][1], Bm0, acc1, 0, 0, 0);
        acc0 = __builtin_amdgcn_mfma_f32_16x16x32_bf16(A[0][0][0], Bl0, acc0, 0, 0, 0);
        acc1 = __builtin_amdgcn_mfma_f32_16x16x32_bf16(A[1][0][0], Bl0, acc1, 0, 0, 0);
        acc0 = __builtin_amdgcn_mfma_f32_16x16x32_bf16(A[0][1][0], Bh1, acc0, 0, 0, 0);
        acc1 = __builtin_amdgcn_mfma_f32_16x16x32_bf16(A[1][1][0], Bh1, acc1, 0, 0, 0);
        acc0 = __builtin_amdgcn_mfma_f32_16x16x32_bf16(A[0][1][1], Bh1, acc0, 0, 0, 0);
        acc1 = __builtin_amdgcn_mfma_f32_16x16x32_bf16(A[1][1][1], Bh1, acc1, 0, 0, 0);
        acc0 = __builtin_amdgcn_mfma_f32_16x16x32_bf16(A[0][1][2], Bh1, acc0, 0, 0, 0);
        acc1 = __builtin_amdgcn_mfma_f32_16x16x32_bf16(A[1][1][2], Bh1, acc1, 0, 0, 0);
        acc0 = __builtin_amdgcn_mfma_f32_16x16x32_bf16(A[0][1][1], Bm1, acc0, 0, 0, 0);
        acc1 = __builtin_amdgcn_mfma_f32_16x16x32_bf16(A[1][1][1], Bm1, acc1, 0, 0, 0);
        acc0 = __builtin_amdgcn_mfma_f32_16x16x32_bf16(A[0][1][0], Bm1, acc0, 0, 0, 0);
        acc1 = __builtin_amdgcn_mfma_f32_16x16x32_bf16(A[1][1][0], Bm1, acc1, 0, 0, 0);
        acc0 = __builtin_amdgcn_mfma_f32_16x16x32_bf16(A[0][1][0], Bl1, acc0, 0, 0, 0);
        acc1 = __builtin_amdgcn_mfma_f32_16x16x32_bf16(A[1][1][0], Bl1, acc1, 0, 0, 0);
        __builtin_amdgcn_s_setprio(0);

        // ---- hand off to next phase's fold ----
        pacc0 = acc0; pacc1 = acc1; e2prev = e2v; tprev = t;
    }

    // ---- epilogue: fold the last phase ----
#pragma unroll
    for (int v = 0; v < 4; ++v) {
        float d0 = fmaf(-2.0f, pacc0[v], e2prev);
        if (d0 < bestd[v])     { bestd[v]     = d0; bt[v]     = tprev; }
        float d1 = fmaf(-2.0f, pacc1[v], e2prev);
        if (d1 < bestd[4 + v]) { bestd[4 + v] = d1; bt[4 + v] = tprev; }
    }

    // ---- cross-lane min over the 16 cw-lanes, then atomicMin merge ----
    // (u64 pack: min dist, tie -> min cw == first occurrence; visit-order
    //  independent, so the tile-offset stagger is safe.)
#pragma unroll
    for (int mt = 0; mt < 2; ++mt) {
#pragma unroll
        for (int v = 0; v < 4; ++v) {
            float bd = bestd[mt * 4 + v];
            int   cw = chunkbase + bt[mt * 4 + v] * 16 + l15;
            unsigned db = __float_as_uint(bd);
            db = (db & 0x80000000u) ? ~db : (db | 0x80000000u);
            unsigned long long key =
                ((unsigned long long)db << 32) | (unsigned)cw;
#pragma unroll
            for (int off2 = 1; off2 < 16; off2 <<= 1) {
                unsigned long long o = __shfl_xor(key, off2);
                key = (o < key) ? o : key;
            }
            if (l15 == 0)
                atomicMin(&best[rowbase + mt * 16 + l4 * 4 + v], key);
        }
    }
}

// -------- kernel 3: gather + straight-through output + fused loss -----
// Last-finishing block (device-scope counter) finalizes the loss:
// writers do lsum-add -> threadfence -> counter-add (release); the last
// block sees counter==grid-1, fences, re-reads the complete sum.
__global__ __launch_bounds__(256) void vq_out_kernel(
    const float* __restrict__ z, const float* __restrict__ emb,
    const unsigned long long* __restrict__ best,
    float* __restrict__ out, float* __restrict__ lsum,
    unsigned* __restrict__ counter) {
    const int base = (blockIdx.x * 256 + threadIdx.x) * 8;
    const int row  = base >> 6;
    const int m    = (int)(best[row] & 0xFFFFFFFFull);

    const float4* zp = reinterpret_cast<const float4*>(z + base);
    const float4* qp = reinterpret_cast<const float4*>(emb + (size_t)m * WORD + (base & 63));
    float4* op = reinterpret_cast<float4*>(out + base);

    float s = 0.f;
#pragma unroll
    for (int i = 0; i < 2; ++i) {
        float4 zv = zp[i];
        float4 qv = qp[i];
        float dx = qv.x - zv.x, dy = qv.y - zv.y, dz = qv.z - zv.z, dw = qv.w - zv.w;
        float4 ov;
        ov.x = zv.x + dx; ov.y = zv.y + dy; ov.z = zv.z + dz; ov.w = zv.w + dw;
        op[i] = ov;
        s += dx*dx + dy*dy + dz*dz + dw*dw;
    }

#pragma unroll
    for (int off = 32; off > 0; off >>= 1) s += __shfl_down(s, off);
    __shared__ float wsum[4];
    int lane = threadIdx.x & 63, wid = threadIdx.x >> 6;
    if (lane == 0) wsum[wid] = s;
    __syncthreads();
    if (threadIdx.x == 0) {
        float bsum = (wsum[0] + wsum[1]) + (wsum[2] + wsum[3]);
        atomicAdd(lsum, bsum);
        __threadfence();                       // lsum-add before counter-add
        unsigned old = atomicAdd(counter, 1u);
        if (old == (unsigned)(OUT_GRID - 1)) {
            __threadfence();                   // all lsum-adds now visible
            float total = atomicAdd(lsum, 0.0f);   // device-scope read
            float mean  = total * (1.0f / (float)NELEM);
            out[NELEM]  = mean + 2.5f * mean;
        }
    }
}

extern "C" void kernel_launch(void* const* d_in, const int* in_sizes, int n_in,
                              void* d_out, int out_size, void* d_ws, size_t ws_size,
                              hipStream_t stream) {
    const float* z   = (const float*)d_in[0];   // z_mean (2048,1024)
    // d_in[1] = z_log_var, unused by the reference
    const float* emb = (const float*)d_in[2];   // (8192,64)
    float* out = (float*)d_out;                 // [z_q_st flat (2097152), loss]

    // ws layout: epack 3 MB | e2 32 KB | best 256 KB | lsum 4 B | counter 4 B
    bf16x8* epack = (bf16x8*)d_ws;
    float*  e2    = (float*)((char*)d_ws + (size_t)PKTS * 16);
    unsigned long long* best =
        (unsigned long long*)((char*)e2 + NB_WORD * sizeof(float));
    float*    lsum    = (float*)((char*)best + NROWS * sizeof(unsigned long long));
    unsigned* counter = (unsigned*)(lsum + 1);

    vq_prep_kernel<<<NB_WORD / 256, 256, 0, stream>>>(
        emb, e2, epack, best, lsum, counter);
    vq_argmin_kernel<<<dim3(NROWS / 128, NCHUNK), 256, 0, stream>>>(
        z, epack, e2, best);
    vq_out_kernel<<<OUT_GRID, 256, 0, stream>>>(
        z, emb, best, out, lsum, counter);
}